// Round 12
// baseline (35.727 us; speedup 1.0000x reference)
//
#include <hip/hip_runtime.h>

// ROI Align (B=8, H=32, W=32, C=256 NHWC fp32; R=128 ROIs; 7x7 out, 2x2 samples).
//
// Round 12: LAUNCH-OVERHEAD PROBE. Identical kernel to round 11 (verified,
// 21.2us), launched TWICE in the same graph. The kernel is a pure function of
// the inputs (second launch rewrites identical values), so this is
// deterministic and correctness-safe.
//   kernel_true ~= dur(2x) - 21.2 ; overhead ~= 21.2 - kernel_true.
// dur ~42 -> no overhead, keep optimizing. dur ~32 -> ~10us fixed overhead,
// kernel is already at its ~11-13us memory floor -> revert + declare.

#define NB 8
#define NH 32
#define NW 32
#define NR 128

typedef float f32x4 __attribute__((ext_vector_type(4)));

__device__ __forceinline__ float4 lerp4(float4 a, float4 b, float w) {
    float4 r;
    r.x = a.x + (b.x - a.x) * w;
    r.y = a.y + (b.y - a.y) * w;
    r.z = a.z + (b.z - a.z) * w;
    r.w = a.w + (b.w - a.w) * w;
    return r;
}

template<int DY>
__device__ __forceinline__ void roi_row_proc(
    const float4* __restrict__ basep,     // fm4 + batch offset + lane
    int ro0, int ro1, int ro2, int ro3,   // clamped row offsets (float4 units)
    int xlo, float basex, float stepx,
    float wy0, float wy1,
    float4* __restrict__ outp)            // out4 + (n*49+oy*7)*64 + lane
{
    float4 ring[4][4];

#define LOADSLOT(S, cidx) do {                                   \
        int xo_ = (min((cidx), NW - 1)) << 6;                    \
        ring[S][0] = basep[ro0 + xo_];                           \
        ring[S][1] = basep[ro1 + xo_];                           \
        if constexpr (DY >= 1) ring[S][2] = basep[ro2 + xo_];    \
        if constexpr (DY == 2) ring[S][3] = basep[ro3 + xo_];    \
    } while (0)

    LOADSLOT(0, xlo);
    LOADSLOT(1, xlo + 1);
    LOADSLOT(2, xlo + 2);
    LOADSLOT(3, xlo + 3);

    unsigned long long cnt3v = 0;
    int lastci_v = 0;
    #pragma unroll
    for (int s2 = 0; s2 < 14; ++s2) {
        float xsf = fmaf((float)s2, stepx, basex);
        int gi = (int)floorf(xsf);
        cnt3v += 1ull << (3 * (gi - xlo));
        lastci_v = gi - xlo;               // floors monotone; final = max
    }
    int lastci = __builtin_amdgcn_readfirstlane(lastci_v);
    unsigned c3lo = __builtin_amdgcn_readfirstlane((unsigned)cnt3v);
    unsigned c3hi = __builtin_amdgcn_readfirstlane((unsigned)(cnt3v >> 32));
    unsigned long long cnt3 = ((unsigned long long)c3hi << 32) | c3lo;

    auto VSUM = [&](int S) -> float4 {
        float4 lo = lerp4(ring[S][0], ring[S][1], wy0);
        float4 hi;
        if constexpr (DY == 0)      hi = lerp4(ring[S][0], ring[S][1], wy1);
        else if constexpr (DY == 1) hi = lerp4(ring[S][1], ring[S][2], wy1);
        else                        hi = lerp4(ring[S][2], ring[S][3], wy1);
        float4 v;
        v.x = lo.x + hi.x; v.y = lo.y + hi.y;
        v.z = lo.z + hi.z; v.w = lo.w + hi.w;
        return v;
    };

    float4 va = VSUM(0);
    float sf = 0.0f;
    int srun = 0;
    float4 acc = make_float4(0.f, 0.f, 0.f, 0.f);

    #pragma unroll
    for (int ci = 0; ci < 15; ++ci) {        // STATIC trip count — no break
        float4 vb = VSUM((ci + 1) & 3);
        if (ci <= 11 && ci <= lastci - 3) LOADSLOT(ci & 3, xlo + ci + 4);
        int c = (int)((cnt3 >> (3 * ci)) & 7);
        for (int k = 0; k < c; ++k) {
            float xsf = fmaf(sf, stepx, basex);   // bit-identical to precompute
            float wx = xsf - (float)(xlo + ci);   // exact: floor(xsf)==xlo+ci
            float4 p = lerp4(va, vb, wx);
            if ((srun & 1) == 0) {
                acc = p;
            } else {
                f32x4 r;
                r.x = (acc.x + p.x) * 0.25f;
                r.y = (acc.y + p.y) * 0.25f;
                r.z = (acc.z + p.z) * 0.25f;
                r.w = (acc.w + p.w) * 0.25f;
                __builtin_nontemporal_store(r, (f32x4*)(outp + ((srun >> 1) << 6)));
            }
            ++srun;
            sf += 1.0f;
        }
        va = vb;
    }
#undef LOADSLOT
}

__global__ __launch_bounds__(256) void roi_align_nt(
    const float* __restrict__ fm,
    const float* __restrict__ boxes,
    float* __restrict__ out)
{
    int bid = blockIdx.x;
    int newbid = (bid & 7) * 224 + (bid >> 3);   // XCD -> batch locality
    int t = threadIdx.x;
    int lane = t & 63;                           // channel float4 group
    int g = newbid * 4 + (t >> 6);               // wave id 0..7167 = (n, oy)
    int n = (int)(((unsigned)g * 9363u) >> 16);  // g / 7 (exact for g < 7168)
    int oy = g - n * 7;
    int b = n >> 7;

    float bx0 = boxes[n * 4 + 0] * (1.0f / 31.0f);
    float by0 = boxes[n * 4 + 1] * (1.0f / 31.0f);
    float bx1 = boxes[n * 4 + 2] * (1.0f / 31.0f);
    float by1 = boxes[n * 4 + 3] * (1.0f / 31.0f);
    float x1 = fmaxf(bx0, 0.0f), y1 = fmaxf(by0, 0.0f);
    float x2 = fminf(bx1, 1.0f), y2 = fminf(by1, 1.0f);
    float bin_h = (y2 - y1) / 7.0f;
    float bin_w = (x2 - x1) / 7.0f;
    float gy1 = y1 + 0.25f * bin_h;
    float gx1 = x1 + 0.25f * bin_w;
    float gy2 = y2 - 0.25f * bin_h;
    float gx2 = x2 - 0.25f * bin_w;
    float basey = gy1 * 31.0f;
    float basex = gx1 * 31.0f;
    float stepy = (gy2 - gy1) * (31.0f / 13.0f);
    float stepx = (gx2 - gx1) * (31.0f / 13.0f);

    float ysf0 = basey + (float)(2 * oy) * stepy;
    float ysf1 = basey + (float)(2 * oy + 1) * stepy;
    float f0f = floorf(ysf0);
    float f1f = floorf(ysf1);
    float wy0 = ysf0 - f0f;
    float wy1 = ysf1 - f1f;
    int f0 = (int)f0f;                                        // >= 0, <= 30
    int dy = __builtin_amdgcn_readfirstlane((int)f1f - f0);   // 0, 1, or 2

    const float4* fm4 = (const float4*)fm;
    const float4* basep = fm4 + (size_t)b * (NH * NW * 64) + lane;
    int ro0 = (min(f0,     NH - 1) * NW) << 6;
    int ro1 = (min(f0 + 1, NH - 1) * NW) << 6;
    int ro2 = (min(f0 + 2, NH - 1) * NW) << 6;
    int ro3 = (min(f0 + 3, NH - 1) * NW) << 6;

    int xlo = __builtin_amdgcn_readfirstlane((int)floorf(basex));
    float4* outp = (float4*)out + (n * 49 + oy * 7) * 64 + lane;

    if (dy == 0)      roi_row_proc<0>(basep, ro0, ro1, ro2, ro3, xlo, basex, stepx, wy0, wy1, outp);
    else if (dy == 1) roi_row_proc<1>(basep, ro0, ro1, ro2, ro3, xlo, basex, stepx, wy0, wy1, outp);
    else              roi_row_proc<2>(basep, ro0, ro1, ro2, ro3, xlo, basex, stepx, wy0, wy1, outp);
}

extern "C" void kernel_launch(void* const* d_in, const int* in_sizes, int n_in,
                              void* d_out, int out_size, void* d_ws, size_t ws_size,
                              hipStream_t stream) {
    const float* fm    = (const float*)d_in[0];
    const float* boxes = (const float*)d_in[1];
    float* out = (float*)d_out;

    // PROBE: two identical launches. Second recomputes identical output
    // (pure function of inputs) — deterministic, correctness-unchanged.
    // kernel_true ~= dur(this) - dur(round 11).
    roi_align_nt<<<1792, 256, 0, stream>>>(fm, boxes, out);
    roi_align_nt<<<1792, 256, 0, stream>>>(fm, boxes, out);
}

// Round 13
// 20.342 us; speedup vs baseline: 1.7563x; 1.7563x over previous
//
#include <hip/hip_runtime.h>

// ROI Align (B=8, H=32, W=32, C=256 NHWC fp32; R=128 ROIs; 7x7 out, 2x2 samples).
//
// Round 13: round-11 body (verified, kernel_true ~14.5us per round-12 probe),
// launched as 64-thread blocks (1 wave per block, 7168 blocks) instead of
// 256-thread blocks. Waves have variable work (span 6-15 cols, dy paths);
// 1-wave blocks let the scheduler pack/retire them independently instead of
// quantizing on the slowest wave of each 4-wave block -> better VALU/VMEM
// overlap at the same byte counts. Single launch (round-12 probe reverted).

#define NB 8
#define NH 32
#define NW 32
#define NR 128

typedef float f32x4 __attribute__((ext_vector_type(4)));

__device__ __forceinline__ float4 lerp4(float4 a, float4 b, float w) {
    float4 r;
    r.x = a.x + (b.x - a.x) * w;
    r.y = a.y + (b.y - a.y) * w;
    r.z = a.z + (b.z - a.z) * w;
    r.w = a.w + (b.w - a.w) * w;
    return r;
}

template<int DY>
__device__ __forceinline__ void roi_row_proc(
    const float4* __restrict__ basep,     // fm4 + batch offset + lane
    int ro0, int ro1, int ro2, int ro3,   // clamped row offsets (float4 units)
    int xlo, float basex, float stepx,
    float wy0, float wy1,
    float4* __restrict__ outp)            // out4 + (n*49+oy*7)*64 + lane
{
    float4 ring[4][4];

#define LOADSLOT(S, cidx) do {                                   \
        int xo_ = (min((cidx), NW - 1)) << 6;                    \
        ring[S][0] = basep[ro0 + xo_];                           \
        ring[S][1] = basep[ro1 + xo_];                           \
        if constexpr (DY >= 1) ring[S][2] = basep[ro2 + xo_];    \
        if constexpr (DY == 2) ring[S][3] = basep[ro3 + xo_];    \
    } while (0)

    LOADSLOT(0, xlo);
    LOADSLOT(1, xlo + 1);
    LOADSLOT(2, xlo + 2);
    LOADSLOT(3, xlo + 3);

    // Per-column consume counts in VALU (all lanes identical); 3
    // readfirstlanes at the end. gi - xlo in [0,14]; <= 4 samples/col.
    unsigned long long cnt3v = 0;
    int lastci_v = 0;
    #pragma unroll
    for (int s2 = 0; s2 < 14; ++s2) {
        float xsf = fmaf((float)s2, stepx, basex);
        int gi = (int)floorf(xsf);
        cnt3v += 1ull << (3 * (gi - xlo));
        lastci_v = gi - xlo;               // floors monotone; final = max
    }
    int lastci = __builtin_amdgcn_readfirstlane(lastci_v);
    unsigned c3lo = __builtin_amdgcn_readfirstlane((unsigned)cnt3v);
    unsigned c3hi = __builtin_amdgcn_readfirstlane((unsigned)(cnt3v >> 32));
    unsigned long long cnt3 = ((unsigned long long)c3hi << 32) | c3lo;

    auto VSUM = [&](int S) -> float4 {
        float4 lo = lerp4(ring[S][0], ring[S][1], wy0);
        float4 hi;
        if constexpr (DY == 0)      hi = lerp4(ring[S][0], ring[S][1], wy1);
        else if constexpr (DY == 1) hi = lerp4(ring[S][1], ring[S][2], wy1);
        else                        hi = lerp4(ring[S][2], ring[S][3], wy1);
        float4 v;
        v.x = lo.x + hi.x; v.y = lo.y + hi.y;
        v.z = lo.z + hi.z; v.w = lo.w + hi.w;
        return v;
    };

    float4 va = VSUM(0);
    float sf = 0.0f;
    int srun = 0;
    float4 acc = make_float4(0.f, 0.f, 0.f, 0.f);

    #pragma unroll
    for (int ci = 0; ci < 15; ++ci) {        // STATIC trip count — no break
        float4 vb = VSUM((ci + 1) & 3);
        if (ci <= 11 && ci <= lastci - 3) LOADSLOT(ci & 3, xlo + ci + 4);
        int c = (int)((cnt3 >> (3 * ci)) & 7);
        for (int k = 0; k < c; ++k) {
            float xsf = fmaf(sf, stepx, basex);   // bit-identical to precompute
            float wx = xsf - (float)(xlo + ci);   // exact: floor(xsf)==xlo+ci
            float4 p = lerp4(va, vb, wx);
            if ((srun & 1) == 0) {
                acc = p;
            } else {
                f32x4 r;
                r.x = (acc.x + p.x) * 0.25f;
                r.y = (acc.y + p.y) * 0.25f;
                r.z = (acc.z + p.z) * 0.25f;
                r.w = (acc.w + p.w) * 0.25f;
                __builtin_nontemporal_store(r, (f32x4*)(outp + ((srun >> 1) << 6)));
            }
            ++srun;
            sf += 1.0f;
        }
        va = vb;
    }
#undef LOADSLOT
}

__global__ __launch_bounds__(64) void roi_align_w64(
    const float* __restrict__ fm,
    const float* __restrict__ boxes,
    float* __restrict__ out)
{
    // One wave per block. 7168 blocks = 1024 ROIs x 7 oy rows.
    // XCD swizzle: XCD (= blockIdx % 8, round-robin) gets a contiguous chunk
    // of 896 waves == exactly one batch (b = g/896/... = g>>? 896*8=7168,
    // g in [xcd*896, xcd*896+896) -> n in [xcd*128, xcd*128+128) -> b == xcd).
    int bid = blockIdx.x;
    int g = (bid & 7) * 896 + (bid >> 3);        // wave id 0..7167 = (n, oy)
    int lane = threadIdx.x;                      // channel float4 group
    int n = (int)(((unsigned)g * 9363u) >> 16);  // g / 7 (exact for g < 7168)
    int oy = g - n * 7;
    int b = n >> 7;

    // Box math — identical to all verified rounds.
    float bx0 = boxes[n * 4 + 0] * (1.0f / 31.0f);
    float by0 = boxes[n * 4 + 1] * (1.0f / 31.0f);
    float bx1 = boxes[n * 4 + 2] * (1.0f / 31.0f);
    float by1 = boxes[n * 4 + 3] * (1.0f / 31.0f);
    float x1 = fmaxf(bx0, 0.0f), y1 = fmaxf(by0, 0.0f);
    float x2 = fminf(bx1, 1.0f), y2 = fminf(by1, 1.0f);
    float bin_h = (y2 - y1) / 7.0f;
    float bin_w = (x2 - x1) / 7.0f;
    float gy1 = y1 + 0.25f * bin_h;
    float gx1 = x1 + 0.25f * bin_w;
    float gy2 = y2 - 0.25f * bin_h;
    float gx2 = x2 - 0.25f * bin_w;
    float basey = gy1 * 31.0f;
    float basex = gx1 * 31.0f;
    float stepy = (gy2 - gy1) * (31.0f / 13.0f);
    float stepx = (gx2 - gx1) * (31.0f / 13.0f);

    float ysf0 = basey + (float)(2 * oy) * stepy;
    float ysf1 = basey + (float)(2 * oy + 1) * stepy;
    float f0f = floorf(ysf0);
    float f1f = floorf(ysf1);
    float wy0 = ysf0 - f0f;
    float wy1 = ysf1 - f1f;
    int f0 = (int)f0f;                                        // >= 0, <= 30
    int dy = __builtin_amdgcn_readfirstlane((int)f1f - f0);   // 0, 1, or 2

    const float4* fm4 = (const float4*)fm;
    const float4* basep = fm4 + (size_t)b * (NH * NW * 64) + lane;
    int ro0 = (min(f0,     NH - 1) * NW) << 6;
    int ro1 = (min(f0 + 1, NH - 1) * NW) << 6;
    int ro2 = (min(f0 + 2, NH - 1) * NW) << 6;
    int ro3 = (min(f0 + 3, NH - 1) * NW) << 6;

    int xlo = __builtin_amdgcn_readfirstlane((int)floorf(basex));
    float4* outp = (float4*)out + (n * 49 + oy * 7) * 64 + lane;

    if (dy == 0)      roi_row_proc<0>(basep, ro0, ro1, ro2, ro3, xlo, basex, stepx, wy0, wy1, outp);
    else if (dy == 1) roi_row_proc<1>(basep, ro0, ro1, ro2, ro3, xlo, basex, stepx, wy0, wy1, outp);
    else              roi_row_proc<2>(basep, ro0, ro1, ro2, ro3, xlo, basex, stepx, wy0, wy1, outp);
}

extern "C" void kernel_launch(void* const* d_in, const int* in_sizes, int n_in,
                              void* d_out, int out_size, void* d_ws, size_t ws_size,
                              hipStream_t stream) {
    const float* fm    = (const float*)d_in[0];
    const float* boxes = (const float*)d_in[1];
    float* out = (float*)d_out;

    // 7168 one-wave blocks = 1024 ROIs x 7 oy rows.
    roi_align_w64<<<7168, 64, 0, stream>>>(fm, boxes, out);
}

// Round 14
// 19.688 us; speedup vs baseline: 1.8147x; 1.0332x over previous
//
#include <hip/hip_runtime.h>

// ROI Align (B=8, H=32, W=32, C=256 NHWC fp32; R=128 ROIs; 7x7 out, 2x2 samples).
//
// Round 14: round-13 (verified, 20.3us) + dead-iteration predication.
//  - The static 15-trip column loop ran ~4 dead iterations past lastci
//    (avg span ~11 cols), each paying a full VSUM (~24 VALU ops). Round 10
//    proved wave-uniform predicates inside the unroll are register-safe
//    (unlike round 9's break, which collapsed the unroll -> scratch).
//    Now the whole iteration body is guarded by `if (ci <= lastci)` —
//    uniform SGPR branch, static trip count, ring indices compile-time.
//  - Everything else identical to round 13: 64-thread blocks (1 wave each,
//    7168 blocks), separable vsum per column, packed 3-bit consume counts
//    (VALU-side, 3 readfirstlanes), fmaf-consistent wx reconstruction,
//    depth-4 column ring (slot = col mod 4), dy in {0,1,2} templates,
//    NT stores, XCD swizzle (blockIdx%8 == batch).

#define NB 8
#define NH 32
#define NW 32
#define NR 128

typedef float f32x4 __attribute__((ext_vector_type(4)));

__device__ __forceinline__ float4 lerp4(float4 a, float4 b, float w) {
    float4 r;
    r.x = a.x + (b.x - a.x) * w;
    r.y = a.y + (b.y - a.y) * w;
    r.z = a.z + (b.z - a.z) * w;
    r.w = a.w + (b.w - a.w) * w;
    return r;
}

template<int DY>
__device__ __forceinline__ void roi_row_proc(
    const float4* __restrict__ basep,     // fm4 + batch offset + lane
    int ro0, int ro1, int ro2, int ro3,   // clamped row offsets (float4 units)
    int xlo, float basex, float stepx,
    float wy0, float wy1,
    float4* __restrict__ outp)            // out4 + (n*49+oy*7)*64 + lane
{
    float4 ring[4][4];

#define LOADSLOT(S, cidx) do {                                   \
        int xo_ = (min((cidx), NW - 1)) << 6;                    \
        ring[S][0] = basep[ro0 + xo_];                           \
        ring[S][1] = basep[ro1 + xo_];                           \
        if constexpr (DY >= 1) ring[S][2] = basep[ro2 + xo_];    \
        if constexpr (DY == 2) ring[S][3] = basep[ro3 + xo_];    \
    } while (0)

    LOADSLOT(0, xlo);
    LOADSLOT(1, xlo + 1);
    LOADSLOT(2, xlo + 2);
    LOADSLOT(3, xlo + 3);

    // Per-column consume counts in VALU (all lanes identical); 3
    // readfirstlanes at the end. gi - xlo in [0,14]; <= 4 samples/col.
    unsigned long long cnt3v = 0;
    int lastci_v = 0;
    #pragma unroll
    for (int s2 = 0; s2 < 14; ++s2) {
        float xsf = fmaf((float)s2, stepx, basex);
        int gi = (int)floorf(xsf);
        cnt3v += 1ull << (3 * (gi - xlo));
        lastci_v = gi - xlo;               // floors monotone; final = max
    }
    int lastci = __builtin_amdgcn_readfirstlane(lastci_v);
    unsigned c3lo = __builtin_amdgcn_readfirstlane((unsigned)cnt3v);
    unsigned c3hi = __builtin_amdgcn_readfirstlane((unsigned)(cnt3v >> 32));
    unsigned long long cnt3 = ((unsigned long long)c3hi << 32) | c3lo;

    auto VSUM = [&](int S) -> float4 {
        float4 lo = lerp4(ring[S][0], ring[S][1], wy0);
        float4 hi;
        if constexpr (DY == 0)      hi = lerp4(ring[S][0], ring[S][1], wy1);
        else if constexpr (DY == 1) hi = lerp4(ring[S][1], ring[S][2], wy1);
        else                        hi = lerp4(ring[S][2], ring[S][3], wy1);
        float4 v;
        v.x = lo.x + hi.x; v.y = lo.y + hi.y;
        v.z = lo.z + hi.z; v.w = lo.w + hi.w;
        return v;
    };

    float4 va = VSUM(0);
    float sf = 0.0f;
    int srun = 0;
    float4 acc = make_float4(0.f, 0.f, 0.f, 0.f);

    #pragma unroll
    for (int ci = 0; ci < 15; ++ci) {        // STATIC trip count — no break
        // Wave-uniform predication: skip dead iterations past the span
        // entirely (VSUM + count extraction). Uniform SGPR branch; the loop
        // structure and ring indexing remain fully unrolled/static.
        if (ci <= lastci) {
            float4 vb = VSUM((ci + 1) & 3);
            if (ci <= 11 && ci <= lastci - 3) LOADSLOT(ci & 3, xlo + ci + 4);
            int c = (int)((cnt3 >> (3 * ci)) & 7);
            for (int k = 0; k < c; ++k) {
                float xsf = fmaf(sf, stepx, basex);   // bit-identical to precompute
                float wx = xsf - (float)(xlo + ci);   // exact: floor(xsf)==xlo+ci
                float4 p = lerp4(va, vb, wx);
                if ((srun & 1) == 0) {
                    acc = p;
                } else {
                    f32x4 r;
                    r.x = (acc.x + p.x) * 0.25f;
                    r.y = (acc.y + p.y) * 0.25f;
                    r.z = (acc.z + p.z) * 0.25f;
                    r.w = (acc.w + p.w) * 0.25f;
                    __builtin_nontemporal_store(r, (f32x4*)(outp + ((srun >> 1) << 6)));
                }
                ++srun;
                sf += 1.0f;
            }
            va = vb;
        }
    }
#undef LOADSLOT
}

__global__ __launch_bounds__(64) void roi_align_w64p(
    const float* __restrict__ fm,
    const float* __restrict__ boxes,
    float* __restrict__ out)
{
    // One wave per block. 7168 blocks = 1024 ROIs x 7 oy rows.
    // XCD swizzle: each XCD gets a contiguous 896-wave chunk == one batch.
    int bid = blockIdx.x;
    int g = (bid & 7) * 896 + (bid >> 3);        // wave id 0..7167 = (n, oy)
    int lane = threadIdx.x;                      // channel float4 group
    int n = (int)(((unsigned)g * 9363u) >> 16);  // g / 7 (exact for g < 7168)
    int oy = g - n * 7;
    int b = n >> 7;

    // Box math — identical to all verified rounds.
    float bx0 = boxes[n * 4 + 0] * (1.0f / 31.0f);
    float by0 = boxes[n * 4 + 1] * (1.0f / 31.0f);
    float bx1 = boxes[n * 4 + 2] * (1.0f / 31.0f);
    float by1 = boxes[n * 4 + 3] * (1.0f / 31.0f);
    float x1 = fmaxf(bx0, 0.0f), y1 = fmaxf(by0, 0.0f);
    float x2 = fminf(bx1, 1.0f), y2 = fminf(by1, 1.0f);
    float bin_h = (y2 - y1) / 7.0f;
    float bin_w = (x2 - x1) / 7.0f;
    float gy1 = y1 + 0.25f * bin_h;
    float gx1 = x1 + 0.25f * bin_w;
    float gy2 = y2 - 0.25f * bin_h;
    float gx2 = x2 - 0.25f * bin_w;
    float basey = gy1 * 31.0f;
    float basex = gx1 * 31.0f;
    float stepy = (gy2 - gy1) * (31.0f / 13.0f);
    float stepx = (gx2 - gx1) * (31.0f / 13.0f);

    float ysf0 = basey + (float)(2 * oy) * stepy;
    float ysf1 = basey + (float)(2 * oy + 1) * stepy;
    float f0f = floorf(ysf0);
    float f1f = floorf(ysf1);
    float wy0 = ysf0 - f0f;
    float wy1 = ysf1 - f1f;
    int f0 = (int)f0f;                                        // >= 0, <= 30
    int dy = __builtin_amdgcn_readfirstlane((int)f1f - f0);   // 0, 1, or 2

    const float4* fm4 = (const float4*)fm;
    const float4* basep = fm4 + (size_t)b * (NH * NW * 64) + lane;
    int ro0 = (min(f0,     NH - 1) * NW) << 6;
    int ro1 = (min(f0 + 1, NH - 1) * NW) << 6;
    int ro2 = (min(f0 + 2, NH - 1) * NW) << 6;
    int ro3 = (min(f0 + 3, NH - 1) * NW) << 6;

    int xlo = __builtin_amdgcn_readfirstlane((int)floorf(basex));
    float4* outp = (float4*)out + (n * 49 + oy * 7) * 64 + lane;

    if (dy == 0)      roi_row_proc<0>(basep, ro0, ro1, ro2, ro3, xlo, basex, stepx, wy0, wy1, outp);
    else if (dy == 1) roi_row_proc<1>(basep, ro0, ro1, ro2, ro3, xlo, basex, stepx, wy0, wy1, outp);
    else              roi_row_proc<2>(basep, ro0, ro1, ro2, ro3, xlo, basex, stepx, wy0, wy1, outp);
}

extern "C" void kernel_launch(void* const* d_in, const int* in_sizes, int n_in,
                              void* d_out, int out_size, void* d_ws, size_t ws_size,
                              hipStream_t stream) {
    const float* fm    = (const float*)d_in[0];
    const float* boxes = (const float*)d_in[1];
    float* out = (float*)d_out;

    // 7168 one-wave blocks = 1024 ROIs x 7 oy rows.
    roi_align_w64p<<<7168, 64, 0, stream>>>(fm, boxes, out);
}